// Round 1
// baseline (171.330 us; speedup 1.0000x reference)
//
#include <hip/hip_runtime.h>

typedef __attribute__((ext_vector_type(8))) short bf16x8;
typedef __attribute__((ext_vector_type(4))) float f32x4;

#define N 8192
#define FIN 512
#define FOUT 64

// round-to-nearest-even f32 -> bf16 (inputs are never NaN here)
static __device__ __forceinline__ short f2bf(float x) {
    unsigned u = __float_as_uint(x);
    u += 0x7FFFu + ((u >> 16) & 1u);
    return (short)(u >> 16);
}

// p = adj>0 ? exp(leakyrelu(s, 0.2)) : 0
static __device__ __forceinline__ float pedge(int av, float s) {
    float e = s > 0.f ? s : 0.2f * s;
    float p = __expf(e);
    return av > 0 ? p : 0.f;
}

// Pass A: Wh = h@W (f32 accum); store Wh^T as bf16 [FOUT][N]; f_src/f_dst f32 [N].
// Block = 256 thr (4 waves); block handles 16 rows; wave w -> rows i0+4w..+3; lane = feature.
__global__ __launch_bounds__(256) void gat_prep(const float* __restrict__ h,
    const float* __restrict__ W, const float* __restrict__ a,
    short* __restrict__ WhT, float* __restrict__ fsrc, float* __restrict__ fdst)
{
    __shared__ float lds[FOUT][16];
    const int i0 = blockIdx.x * 16;
    const int w = threadIdx.x >> 6, f = threadIdx.x & 63;
    const int ir = i0 + w * 4;
    const float* h0 = h + (size_t)ir * FIN;
    float acc0 = 0.f, acc1 = 0.f, acc2 = 0.f, acc3 = 0.f;
    for (int k = 0; k < FIN; k += 4) {
        float wv0 = W[(k + 0) * FOUT + f];
        float wv1 = W[(k + 1) * FOUT + f];
        float wv2 = W[(k + 2) * FOUT + f];
        float wv3 = W[(k + 3) * FOUT + f];
        float4 h0v = *(const float4*)(h0 + k);
        float4 h1v = *(const float4*)(h0 + FIN + k);
        float4 h2v = *(const float4*)(h0 + 2 * FIN + k);
        float4 h3v = *(const float4*)(h0 + 3 * FIN + k);
        acc0 = fmaf(h0v.w, wv3, fmaf(h0v.z, wv2, fmaf(h0v.y, wv1, fmaf(h0v.x, wv0, acc0))));
        acc1 = fmaf(h1v.w, wv3, fmaf(h1v.z, wv2, fmaf(h1v.y, wv1, fmaf(h1v.x, wv0, acc1))));
        acc2 = fmaf(h2v.w, wv3, fmaf(h2v.z, wv2, fmaf(h2v.y, wv1, fmaf(h2v.x, wv0, acc2))));
        acc3 = fmaf(h3v.w, wv3, fmaf(h3v.z, wv2, fmaf(h3v.y, wv1, fmaf(h3v.x, wv0, acc3))));
    }
    // f_src / f_dst: reduce acc_r * a over 64 lanes
    const float as = a[f], ad = a[FOUT + f];
    float s0 = acc0 * as, s1 = acc1 * as, s2 = acc2 * as, s3 = acc3 * as;
    float d0 = acc0 * ad, d1 = acc1 * ad, d2 = acc2 * ad, d3 = acc3 * ad;
    #pragma unroll
    for (int m = 1; m < 64; m <<= 1) {
        s0 += __shfl_xor(s0, m); s1 += __shfl_xor(s1, m);
        s2 += __shfl_xor(s2, m); s3 += __shfl_xor(s3, m);
        d0 += __shfl_xor(d0, m); d1 += __shfl_xor(d1, m);
        d2 += __shfl_xor(d2, m); d3 += __shfl_xor(d3, m);
    }
    if (f == 0) {
        fsrc[ir + 0] = s0; fsrc[ir + 1] = s1; fsrc[ir + 2] = s2; fsrc[ir + 3] = s3;
        fdst[ir + 0] = d0; fdst[ir + 1] = d1; fdst[ir + 2] = d2; fdst[ir + 3] = d3;
    }
    // transpose via LDS, write Wh^T bf16
    lds[f][w * 4 + 0] = acc0;
    lds[f][w * 4 + 1] = acc1;
    lds[f][w * 4 + 2] = acc2;
    lds[f][w * 4 + 3] = acc3;
    __syncthreads();
    const int ff = threadIdx.x >> 2, q = threadIdx.x & 3;
    short4 o;
    o.x = f2bf(lds[ff][q * 4 + 0]);
    o.y = f2bf(lds[ff][q * 4 + 1]);
    o.z = f2bf(lds[ff][q * 4 + 2]);
    o.w = f2bf(lds[ff][q * 4 + 3]);
    *(short4*)(WhT + (size_t)ff * N + i0 + q * 4) = o;
}

// Pass B: one block = 64 rows x jlen cols. 4 waves, wave w -> rows [i0+16w, +16).
// Lane l: A-row = l&15, k-group g = l>>4 (8 consecutive j per group).
// num += P_hat @ Wh via mfma_f32_16x16x32_bf16; den += sum(P_hat) in f32.
__global__ __launch_bounds__(256) void gat_main(const int* __restrict__ adj,
    const float* __restrict__ fsrc, const float* __restrict__ fdst,
    const short* __restrict__ WhT, float* __restrict__ nump, float* __restrict__ denp,
    int jsplit, int jlen)
{
    const int ib = blockIdx.x / jsplit;
    const int js = blockIdx.x % jsplit;
    const int i0 = ib * 64, jb = js * jlen;
    const int l = threadIdx.x & 63, w = threadIdx.x >> 6;
    const int rl = l & 15, g = l >> 4;
    const int i = i0 + w * 16 + rl;
    const float fs = fsrc[i];
    const int* arow = adj + (size_t)i * N;
    const short* bbase = WhT + (size_t)rl * N;
    f32x4 acc0{0.f, 0.f, 0.f, 0.f}, acc1{0.f, 0.f, 0.f, 0.f};
    f32x4 acc2{0.f, 0.f, 0.f, 0.f}, acc3{0.f, 0.f, 0.f, 0.f};
    float den = 0.f;
    const int nsteps = jlen >> 5;
    const int jg0 = jb + g * 8;
    for (int s = 0; s < nsteps; ++s) {
        const int jg = jg0 + s * 32;
        int4 a0 = *(const int4*)(arow + jg);
        int4 a1 = *(const int4*)(arow + jg + 4);
        float4 e0 = *(const float4*)(fdst + jg);
        float4 e1 = *(const float4*)(fdst + jg + 4);
        float p0 = pedge(a0.x, fs + e0.x);
        float p1 = pedge(a0.y, fs + e0.y);
        float p2 = pedge(a0.z, fs + e0.z);
        float p3 = pedge(a0.w, fs + e0.w);
        float p4 = pedge(a1.x, fs + e1.x);
        float p5 = pedge(a1.y, fs + e1.y);
        float p6 = pedge(a1.z, fs + e1.z);
        float p7 = pedge(a1.w, fs + e1.w);
        den += ((p0 + p1) + (p2 + p3)) + ((p4 + p5) + (p6 + p7));
        bf16x8 af;
        af[0] = f2bf(p0); af[1] = f2bf(p1); af[2] = f2bf(p2); af[3] = f2bf(p3);
        af[4] = f2bf(p4); af[5] = f2bf(p5); af[6] = f2bf(p6); af[7] = f2bf(p7);
        bf16x8 b0 = *(const bf16x8*)(bbase + jg);
        bf16x8 b1 = *(const bf16x8*)(bbase + 16 * N + jg);
        bf16x8 b2 = *(const bf16x8*)(bbase + 32 * N + jg);
        bf16x8 b3 = *(const bf16x8*)(bbase + 48 * N + jg);
        acc0 = __builtin_amdgcn_mfma_f32_16x16x32_bf16(af, b0, acc0, 0, 0, 0);
        acc1 = __builtin_amdgcn_mfma_f32_16x16x32_bf16(af, b1, acc1, 0, 0, 0);
        acc2 = __builtin_amdgcn_mfma_f32_16x16x32_bf16(af, b2, acc2, 0, 0, 0);
        acc3 = __builtin_amdgcn_mfma_f32_16x16x32_bf16(af, b3, acc3, 0, 0, 0);
    }
    // den: lanes with same (l&15) hold partials for the same row -> butterfly over bits 4,5
    den += __shfl_xor(den, 16);
    den += __shfl_xor(den, 32);
    if (l < 16) denp[(size_t)js * N + i0 + w * 16 + l] = den;
    // C/D layout: col = l&15, row = (l>>4)*4 + reg
    float* np = nump + (size_t)js * N * FOUT + (size_t)(i0 + w * 16) * FOUT;
    #pragma unroll
    for (int q = 0; q < 4; ++q) {
        const int orow = g * 4 + q;
        np[(size_t)orow * FOUT + 0  + rl] = acc0[q];
        np[(size_t)orow * FOUT + 16 + rl] = acc1[q];
        np[(size_t)orow * FOUT + 32 + rl] = acc2[q];
        np[(size_t)orow * FOUT + 48 + rl] = acc3[q];
    }
}

// Pass C: out = elu(num/den)
__global__ __launch_bounds__(256) void gat_final(const float* __restrict__ nump,
    const float* __restrict__ denp, float* __restrict__ out, int jsplit)
{
    const int t = blockIdx.x * 256 + threadIdx.x;
    const int i = t >> 6;
    float num = 0.f, den = 0.f;
    for (int js = 0; js < jsplit; ++js) {
        num += nump[(size_t)js * N * FOUT + t];
        den += denp[(size_t)js * N + i];
    }
    const float x = num / den;
    out[t] = x > 0.f ? x : expm1f(x);
}

extern "C" void kernel_launch(void* const* d_in, const int* in_sizes, int n_in,
                              void* d_out, int out_size, void* d_ws, size_t ws_size,
                              hipStream_t stream) {
    const float* h   = (const float*)d_in[0];
    const int*   adj = (const int*)d_in[1];
    const float* W   = (const float*)d_in[2];
    const float* a   = (const float*)d_in[3];
    float* out = (float*)d_out;

    char* ws = (char*)d_ws;
    short* WhT  = (short*)ws;                          // 64*8192*2 = 1 MiB
    float* fsrc = (float*)(ws + (size_t)FOUT * N * 2); // 32 KiB
    float* fdst = fsrc + N;                            // 32 KiB
    float* nump = fdst + N;
    const size_t base = (size_t)FOUT * N * 2 + 2 * (size_t)N * 4;
    const size_t per  = (size_t)N * FOUT * 4 + (size_t)N * 4; // num + den per split
    int jsplit = 8;
    while (jsplit > 1 && base + (size_t)jsplit * per > ws_size) jsplit >>= 1;
    float* denp = nump + (size_t)jsplit * N * FOUT;
    const int jlen = N / jsplit;

    gat_prep<<<N / 16, 256, 0, stream>>>(h, W, a, WhT, fsrc, fdst);
    gat_main<<<(N / 64) * jsplit, 256, 0, stream>>>(adj, fsrc, fdst, WhT, nump, denp, jsplit, jlen);
    gat_final<<<(N * FOUT) / 256, 256, 0, stream>>>(nump, denp, out, jsplit);
}

// Round 2
// 164.879 us; speedup vs baseline: 1.0391x; 1.0391x over previous
//
#include <hip/hip_runtime.h>

typedef __attribute__((ext_vector_type(8))) short bf16x8;
typedef __attribute__((ext_vector_type(4))) float f32x4;

#define N 8192
#define FIN 512
#define FOUT 64

// round-to-nearest-even f32 -> bf16 (inputs are never NaN here)
static __device__ __forceinline__ short f2bf(float x) {
    unsigned u = __float_as_uint(x);
    u += 0x7FFFu + ((u >> 16) & 1u);
    return (short)(u >> 16);
}

// p = adj>0 ? exp(leakyrelu(s, 0.2)) : 0
static __device__ __forceinline__ float pedge(int av, float s) {
    float e = s > 0.f ? s : 0.2f * s;
    float p = __expf(e);
    return av > 0 ? p : 0.f;
}

// Pass A: Wh = h@W (f32 accum); store Wh^T as bf16 [FOUT][N]; f_src/f_dst f32 [N].
__global__ __launch_bounds__(256) void gat_prep(const float* __restrict__ h,
    const float* __restrict__ W, const float* __restrict__ a,
    short* __restrict__ WhT, float* __restrict__ fsrc, float* __restrict__ fdst)
{
    __shared__ float lds[FOUT][16];
    const int i0 = blockIdx.x * 16;
    const int w = threadIdx.x >> 6, f = threadIdx.x & 63;
    const int ir = i0 + w * 4;
    const float* h0 = h + (size_t)ir * FIN;
    float acc0 = 0.f, acc1 = 0.f, acc2 = 0.f, acc3 = 0.f;
    for (int k = 0; k < FIN; k += 4) {
        float wv0 = W[(k + 0) * FOUT + f];
        float wv1 = W[(k + 1) * FOUT + f];
        float wv2 = W[(k + 2) * FOUT + f];
        float wv3 = W[(k + 3) * FOUT + f];
        float4 h0v = *(const float4*)(h0 + k);
        float4 h1v = *(const float4*)(h0 + FIN + k);
        float4 h2v = *(const float4*)(h0 + 2 * FIN + k);
        float4 h3v = *(const float4*)(h0 + 3 * FIN + k);
        acc0 = fmaf(h0v.w, wv3, fmaf(h0v.z, wv2, fmaf(h0v.y, wv1, fmaf(h0v.x, wv0, acc0))));
        acc1 = fmaf(h1v.w, wv3, fmaf(h1v.z, wv2, fmaf(h1v.y, wv1, fmaf(h1v.x, wv0, acc1))));
        acc2 = fmaf(h2v.w, wv3, fmaf(h2v.z, wv2, fmaf(h2v.y, wv1, fmaf(h2v.x, wv0, acc2))));
        acc3 = fmaf(h3v.w, wv3, fmaf(h3v.z, wv2, fmaf(h3v.y, wv1, fmaf(h3v.x, wv0, acc3))));
    }
    const float as = a[f], ad = a[FOUT + f];
    float s0 = acc0 * as, s1 = acc1 * as, s2 = acc2 * as, s3 = acc3 * as;
    float d0 = acc0 * ad, d1 = acc1 * ad, d2 = acc2 * ad, d3 = acc3 * ad;
    #pragma unroll
    for (int m = 1; m < 64; m <<= 1) {
        s0 += __shfl_xor(s0, m); s1 += __shfl_xor(s1, m);
        s2 += __shfl_xor(s2, m); s3 += __shfl_xor(s3, m);
        d0 += __shfl_xor(d0, m); d1 += __shfl_xor(d1, m);
        d2 += __shfl_xor(d2, m); d3 += __shfl_xor(d3, m);
    }
    if (f == 0) {
        fsrc[ir + 0] = s0; fsrc[ir + 1] = s1; fsrc[ir + 2] = s2; fsrc[ir + 3] = s3;
        fdst[ir + 0] = d0; fdst[ir + 1] = d1; fdst[ir + 2] = d2; fdst[ir + 3] = d3;
    }
    lds[f][w * 4 + 0] = acc0;
    lds[f][w * 4 + 1] = acc1;
    lds[f][w * 4 + 2] = acc2;
    lds[f][w * 4 + 3] = acc3;
    __syncthreads();
    const int ff = threadIdx.x >> 2, q = threadIdx.x & 3;
    short4 o;
    o.x = f2bf(lds[ff][q * 4 + 0]);
    o.y = f2bf(lds[ff][q * 4 + 1]);
    o.z = f2bf(lds[ff][q * 4 + 2]);
    o.w = f2bf(lds[ff][q * 4 + 3]);
    *(short4*)(WhT + (size_t)ff * N + i0 + q * 4) = o;
}

// Pass B: block = 64 rows x jlen cols, 4 waves (wave w -> rows [i0+16w, +16)).
// Lane l: A-row = l&15, k-group g = l>>4 (8 consecutive j per group).
// adj loads (HBM) software-pipelined one step ahead; fdst/WhT are L2-resident.
__global__ __launch_bounds__(256, 8) void gat_main(const int* __restrict__ adj,
    const float* __restrict__ fsrc, const float* __restrict__ fdst,
    const short* __restrict__ WhT, float* __restrict__ nump, float* __restrict__ denp,
    int jsplit, int jlen)
{
    const int ib = blockIdx.x / jsplit;
    const int js = blockIdx.x % jsplit;
    const int i0 = ib * 64, jb = js * jlen;
    const int l = threadIdx.x & 63, w = threadIdx.x >> 6;
    const int rl = l & 15, g = l >> 4;
    const int i = i0 + w * 16 + rl;
    const float fs = fsrc[i];
    const int* arow = adj + (size_t)i * N;
    const short* bbase = WhT + (size_t)rl * N;
    f32x4 acc0{0.f, 0.f, 0.f, 0.f}, acc1{0.f, 0.f, 0.f, 0.f};
    f32x4 acc2{0.f, 0.f, 0.f, 0.f}, acc3{0.f, 0.f, 0.f, 0.f};
    float den = 0.f;
    const int nsteps = jlen >> 5;
    int jg = jb + g * 8;

    int4 ca0 = *(const int4*)(arow + jg);
    int4 ca1 = *(const int4*)(arow + jg + 4);

    for (int s = 0; s < nsteps; ++s) {
        int4 na0, na1;
        if (s + 1 < nsteps) {               // uniform branch; prefetch next adj
            na0 = *(const int4*)(arow + jg + 32);
            na1 = *(const int4*)(arow + jg + 36);
        }
        float4 e0 = *(const float4*)(fdst + jg);
        float4 e1 = *(const float4*)(fdst + jg + 4);
        bf16x8 b0 = *(const bf16x8*)(bbase + jg);
        bf16x8 b1 = *(const bf16x8*)(bbase + 16 * N + jg);
        bf16x8 b2 = *(const bf16x8*)(bbase + 32 * N + jg);
        bf16x8 b3 = *(const bf16x8*)(bbase + 48 * N + jg);
        float p0 = pedge(ca0.x, fs + e0.x);
        float p1 = pedge(ca0.y, fs + e0.y);
        float p2 = pedge(ca0.z, fs + e0.z);
        float p3 = pedge(ca0.w, fs + e0.w);
        float p4 = pedge(ca1.x, fs + e1.x);
        float p5 = pedge(ca1.y, fs + e1.y);
        float p6 = pedge(ca1.z, fs + e1.z);
        float p7 = pedge(ca1.w, fs + e1.w);
        den += ((p0 + p1) + (p2 + p3)) + ((p4 + p5) + (p6 + p7));
        bf16x8 af;
        af[0] = f2bf(p0); af[1] = f2bf(p1); af[2] = f2bf(p2); af[3] = f2bf(p3);
        af[4] = f2bf(p4); af[5] = f2bf(p5); af[6] = f2bf(p6); af[7] = f2bf(p7);
        acc0 = __builtin_amdgcn_mfma_f32_16x16x32_bf16(af, b0, acc0, 0, 0, 0);
        acc1 = __builtin_amdgcn_mfma_f32_16x16x32_bf16(af, b1, acc1, 0, 0, 0);
        acc2 = __builtin_amdgcn_mfma_f32_16x16x32_bf16(af, b2, acc2, 0, 0, 0);
        acc3 = __builtin_amdgcn_mfma_f32_16x16x32_bf16(af, b3, acc3, 0, 0, 0);
        ca0 = na0; ca1 = na1;
        jg += 32;
    }

    den += __shfl_xor(den, 16);
    den += __shfl_xor(den, 32);
    if (l < 16) denp[(size_t)js * N + i0 + w * 16 + l] = den;
    // C/D layout: col = l&15, row = (l>>4)*4 + reg
    float* np = nump + (size_t)js * N * FOUT + (size_t)(i0 + w * 16) * FOUT;
    #pragma unroll
    for (int q = 0; q < 4; ++q) {
        const int orow = g * 4 + q;
        np[(size_t)orow * FOUT + 0  + rl] = acc0[q];
        np[(size_t)orow * FOUT + 16 + rl] = acc1[q];
        np[(size_t)orow * FOUT + 32 + rl] = acc2[q];
        np[(size_t)orow * FOUT + 48 + rl] = acc3[q];
    }
}

// Pass C: out = elu(num/den)
__global__ __launch_bounds__(256) void gat_final(const float* __restrict__ nump,
    const float* __restrict__ denp, float* __restrict__ out, int jsplit)
{
    const int t = blockIdx.x * 256 + threadIdx.x;
    const int i = t >> 6;
    float num = 0.f, den = 0.f;
    for (int js = 0; js < jsplit; ++js) {
        num += nump[(size_t)js * N * FOUT + t];
        den += denp[(size_t)js * N + i];
    }
    const float x = num / den;
    out[t] = x > 0.f ? x : expm1f(x);
}

extern "C" void kernel_launch(void* const* d_in, const int* in_sizes, int n_in,
                              void* d_out, int out_size, void* d_ws, size_t ws_size,
                              hipStream_t stream) {
    const float* h   = (const float*)d_in[0];
    const int*   adj = (const int*)d_in[1];
    const float* W   = (const float*)d_in[2];
    const float* a   = (const float*)d_in[3];
    float* out = (float*)d_out;

    char* ws = (char*)d_ws;
    short* WhT  = (short*)ws;                          // 64*8192*2 = 1 MiB
    float* fsrc = (float*)(ws + (size_t)FOUT * N * 2); // 32 KiB
    float* fdst = fsrc + N;                            // 32 KiB
    float* nump = fdst + N;
    const size_t base = (size_t)FOUT * N * 2 + 2 * (size_t)N * 4;
    const size_t per  = (size_t)N * FOUT * 4 + (size_t)N * 4; // num + den per split
    int jsplit = 16;                                   // 2048 blocks = 8 blocks/CU
    while (jsplit > 1 && base + (size_t)jsplit * per > ws_size) jsplit >>= 1;
    float* denp = nump + (size_t)jsplit * N * FOUT;
    const int jlen = N / jsplit;

    gat_prep<<<N / 16, 256, 0, stream>>>(h, W, a, WhT, fsrc, fdst);
    gat_main<<<(N / 64) * jsplit, 256, 0, stream>>>(adj, fsrc, fdst, WhT, nump, denp, jsplit, jlen);
    gat_final<<<(N * FOUT) / 256, 256, 0, stream>>>(nump, denp, out, jsplit);
}

// Round 3
// 163.096 us; speedup vs baseline: 1.0505x; 1.0109x over previous
//
#include <hip/hip_runtime.h>

typedef __attribute__((ext_vector_type(8))) short bf16x8;
typedef __attribute__((ext_vector_type(4))) float f32x4;

#define N 8192
#define FIN 512
#define FOUT 64
#define NP (N + 32)        // padded WhT row stride (shorts) — breaks 16KB stride aliasing
#define PACKROW 272        // padded packed-adj row stride (dwords) — breaks 1KB stride

// round-to-nearest-even f32 -> bf16 (inputs are never NaN here)
static __device__ __forceinline__ short f2bf(float x) {
    unsigned u = __float_as_uint(x);
    u += 0x7FFFu + ((u >> 16) & 1u);
    return (short)(u >> 16);
}

// p = bit ? exp(leakyrelu(s, 0.2)) : 0   (lrelu(s) = max(s, 0.2s))
static __device__ __forceinline__ float pbit(unsigned byte, int e, float s) {
    float p = __expf(fmaxf(s, 0.2f * s));
    return ((byte >> e) & 1u) ? p : 0.f;
}

// Pack adj (int32 0/1, [N][N]) -> bitmap [N][PACKROW] dwords, bit b of dword d
// of row i == (adj[i][32d+b] > 0). Fully coalesced dense streaming read.
__global__ __launch_bounds__(256) void gat_pack(const int* __restrict__ adj,
                                                unsigned* __restrict__ packed)
{
    const int w = threadIdx.x >> 6, l = threadIdx.x & 63;
    const int nchunks = (N / 2048) * N;          // 2048-int chunks
    const int nwaves = gridDim.x * 4;
    for (int c = blockIdx.x * 4 + w; c < nchunks; c += nwaves) {
        const int row = c >> 2, cj = (c & 3) * 2048;
        const int* src = adj + (size_t)row * N + cj;
        unsigned d = 0;
        #pragma unroll
        for (int it = 0; it < 32; ++it) {
            int v = src[it * 64 + l];
            unsigned long long m = __ballot(v > 0);   // bit l <-> j = cj + it*64 + l
            unsigned part = (l & 1) ? (unsigned)(m >> 32) : (unsigned)m;
            d = ((l >> 1) == it) ? part : d;          // lane l's output dword
        }
        packed[(size_t)row * PACKROW + (cj >> 5) + l] = d;
    }
}

// Pass A: Wh = h@W (f32 accum); store Wh^T as bf16 [FOUT][NP]; f_src/f_dst f32 [N].
__global__ __launch_bounds__(256) void gat_prep(const float* __restrict__ h,
    const float* __restrict__ W, const float* __restrict__ a,
    short* __restrict__ WhT, float* __restrict__ fsrc, float* __restrict__ fdst)
{
    __shared__ float lds[FOUT][16];
    const int i0 = blockIdx.x * 16;
    const int w = threadIdx.x >> 6, f = threadIdx.x & 63;
    const int ir = i0 + w * 4;
    const float* h0 = h + (size_t)ir * FIN;
    float acc0 = 0.f, acc1 = 0.f, acc2 = 0.f, acc3 = 0.f;
    for (int k = 0; k < FIN; k += 4) {
        float wv0 = W[(k + 0) * FOUT + f];
        float wv1 = W[(k + 1) * FOUT + f];
        float wv2 = W[(k + 2) * FOUT + f];
        float wv3 = W[(k + 3) * FOUT + f];
        float4 h0v = *(const float4*)(h0 + k);
        float4 h1v = *(const float4*)(h0 + FIN + k);
        float4 h2v = *(const float4*)(h0 + 2 * FIN + k);
        float4 h3v = *(const float4*)(h0 + 3 * FIN + k);
        acc0 = fmaf(h0v.w, wv3, fmaf(h0v.z, wv2, fmaf(h0v.y, wv1, fmaf(h0v.x, wv0, acc0))));
        acc1 = fmaf(h1v.w, wv3, fmaf(h1v.z, wv2, fmaf(h1v.y, wv1, fmaf(h1v.x, wv0, acc1))));
        acc2 = fmaf(h2v.w, wv3, fmaf(h2v.z, wv2, fmaf(h2v.y, wv1, fmaf(h2v.x, wv0, acc2))));
        acc3 = fmaf(h3v.w, wv3, fmaf(h3v.z, wv2, fmaf(h3v.y, wv1, fmaf(h3v.x, wv0, acc3))));
    }
    const float as = a[f], ad = a[FOUT + f];
    float s0 = acc0 * as, s1 = acc1 * as, s2 = acc2 * as, s3 = acc3 * as;
    float d0 = acc0 * ad, d1 = acc1 * ad, d2 = acc2 * ad, d3 = acc3 * ad;
    #pragma unroll
    for (int m = 1; m < 64; m <<= 1) {
        s0 += __shfl_xor(s0, m); s1 += __shfl_xor(s1, m);
        s2 += __shfl_xor(s2, m); s3 += __shfl_xor(s3, m);
        d0 += __shfl_xor(d0, m); d1 += __shfl_xor(d1, m);
        d2 += __shfl_xor(d2, m); d3 += __shfl_xor(d3, m);
    }
    if (f == 0) {
        fsrc[ir + 0] = s0; fsrc[ir + 1] = s1; fsrc[ir + 2] = s2; fsrc[ir + 3] = s3;
        fdst[ir + 0] = d0; fdst[ir + 1] = d1; fdst[ir + 2] = d2; fdst[ir + 3] = d3;
    }
    lds[f][w * 4 + 0] = acc0;
    lds[f][w * 4 + 1] = acc1;
    lds[f][w * 4 + 2] = acc2;
    lds[f][w * 4 + 3] = acc3;
    __syncthreads();
    const int ff = threadIdx.x >> 2, q = threadIdx.x & 3;
    short4 o;
    o.x = f2bf(lds[ff][q * 4 + 0]);
    o.y = f2bf(lds[ff][q * 4 + 1]);
    o.z = f2bf(lds[ff][q * 4 + 2]);
    o.w = f2bf(lds[ff][q * 4 + 3]);
    *(short4*)(WhT + (size_t)ff * NP + i0 + q * 4) = o;
}

// Pass B: block = 64 rows x jlen cols, 4 waves (wave w -> rows [i0+16w, +16)).
// Lane l: A-row = l&15, k-group g = l>>4 (8 consecutive j per group).
// adj comes from the bitmap: one dword per row covers a whole 32-j step.
__global__ __launch_bounds__(256) void gat_main(const unsigned* __restrict__ packed,
    const float* __restrict__ fsrc, const float* __restrict__ fdst,
    const short* __restrict__ WhT, float* __restrict__ nump, float* __restrict__ denp,
    int jsplit, int jlen)
{
    const int ib = blockIdx.x / jsplit;
    const int js = blockIdx.x % jsplit;
    const int i0 = ib * 64, jb = js * jlen;
    const int l = threadIdx.x & 63, w = threadIdx.x >> 6;
    const int rl = l & 15, g = l >> 4;
    const int i = i0 + w * 16 + rl;
    const float fs = fsrc[i];
    const unsigned* prow = packed + (size_t)i * PACKROW + (jb >> 5);
    const short* bbase = WhT + (size_t)rl * NP;
    f32x4 acc0{0.f, 0.f, 0.f, 0.f}, acc1{0.f, 0.f, 0.f, 0.f};
    f32x4 acc2{0.f, 0.f, 0.f, 0.f}, acc3{0.f, 0.f, 0.f, 0.f};
    float den = 0.f;
    const int nsteps4 = jlen >> 7;         // 4 steps (128 j) per outer iter
    for (int su = 0; su < nsteps4; ++su) {
        const uint4 bwv = *(const uint4*)(prow + su * 4);
        #pragma unroll
        for (int k = 0; k < 4; ++k) {
            const unsigned dw = (k == 0) ? bwv.x : (k == 1) ? bwv.y : (k == 2) ? bwv.z : bwv.w;
            const unsigned byte = (dw >> (g * 8)) & 0xffu;
            const int jg = jb + (su * 4 + k) * 32 + g * 8;
            float4 e0 = *(const float4*)(fdst + jg);
            float4 e1 = *(const float4*)(fdst + jg + 4);
            bf16x8 b0 = *(const bf16x8*)(bbase + jg);
            bf16x8 b1 = *(const bf16x8*)(bbase + 16 * NP + jg);
            bf16x8 b2 = *(const bf16x8*)(bbase + 32 * NP + jg);
            bf16x8 b3 = *(const bf16x8*)(bbase + 48 * NP + jg);
            float p0 = pbit(byte, 0, fs + e0.x);
            float p1 = pbit(byte, 1, fs + e0.y);
            float p2 = pbit(byte, 2, fs + e0.z);
            float p3 = pbit(byte, 3, fs + e0.w);
            float p4 = pbit(byte, 4, fs + e1.x);
            float p5 = pbit(byte, 5, fs + e1.y);
            float p6 = pbit(byte, 6, fs + e1.z);
            float p7 = pbit(byte, 7, fs + e1.w);
            den += ((p0 + p1) + (p2 + p3)) + ((p4 + p5) + (p6 + p7));
            bf16x8 af;
            af[0] = f2bf(p0); af[1] = f2bf(p1); af[2] = f2bf(p2); af[3] = f2bf(p3);
            af[4] = f2bf(p4); af[5] = f2bf(p5); af[6] = f2bf(p6); af[7] = f2bf(p7);
            acc0 = __builtin_amdgcn_mfma_f32_16x16x32_bf16(af, b0, acc0, 0, 0, 0);
            acc1 = __builtin_amdgcn_mfma_f32_16x16x32_bf16(af, b1, acc1, 0, 0, 0);
            acc2 = __builtin_amdgcn_mfma_f32_16x16x32_bf16(af, b2, acc2, 0, 0, 0);
            acc3 = __builtin_amdgcn_mfma_f32_16x16x32_bf16(af, b3, acc3, 0, 0, 0);
        }
    }
    den += __shfl_xor(den, 16);
    den += __shfl_xor(den, 32);
    if (l < 16) denp[(size_t)js * N + i0 + w * 16 + l] = den;
    // C/D layout: col = l&15, row = (l>>4)*4 + reg
    float* np = nump + (size_t)js * N * FOUT + (size_t)(i0 + w * 16) * FOUT;
    #pragma unroll
    for (int q = 0; q < 4; ++q) {
        const int orow = g * 4 + q;
        np[(size_t)orow * FOUT + 0  + rl] = acc0[q];
        np[(size_t)orow * FOUT + 16 + rl] = acc1[q];
        np[(size_t)orow * FOUT + 32 + rl] = acc2[q];
        np[(size_t)orow * FOUT + 48 + rl] = acc3[q];
    }
}

// Pass C: out = elu(num/den)
__global__ __launch_bounds__(256) void gat_final(const float* __restrict__ nump,
    const float* __restrict__ denp, float* __restrict__ out, int jsplit)
{
    const int t = blockIdx.x * 256 + threadIdx.x;
    const int i = t >> 6;
    float num = 0.f, den = 0.f;
    for (int js = 0; js < jsplit; ++js) {
        num += nump[(size_t)js * N * FOUT + t];
        den += denp[(size_t)js * N + i];
    }
    const float x = num / den;
    out[t] = x > 0.f ? x : expm1f(x);
}

extern "C" void kernel_launch(void* const* d_in, const int* in_sizes, int n_in,
                              void* d_out, int out_size, void* d_ws, size_t ws_size,
                              hipStream_t stream) {
    const float* h   = (const float*)d_in[0];
    const int*   adj = (const int*)d_in[1];
    const float* W   = (const float*)d_in[2];
    const float* a   = (const float*)d_in[3];
    float* out = (float*)d_out;

    char* ws = (char*)d_ws;
    short* WhT      = (short*)ws;                                  // 64*NP*2 ~ 1.03 MiB
    float* fsrc     = (float*)(ws + (size_t)FOUT * NP * 2);        // 32 KiB
    float* fdst     = fsrc + N;                                    // 32 KiB
    unsigned* packed = (unsigned*)(fdst + N);                      // N*PACKROW*4 ~ 8.9 MiB
    float* nump     = (float*)((char*)packed + (size_t)N * PACKROW * 4);
    const size_t base = (size_t)FOUT * NP * 2 + 2 * (size_t)N * 4 + (size_t)N * PACKROW * 4;
    const size_t per  = (size_t)N * FOUT * 4 + (size_t)N * 4;      // num + den per split
    int jsplit = 16;                                               // 2048 blocks = 8/CU
    while (jsplit > 1 && base + (size_t)jsplit * per > ws_size) jsplit >>= 1;
    float* denp = nump + (size_t)jsplit * N * FOUT;
    const int jlen = N / jsplit;

    gat_pack<<<2048, 256, 0, stream>>>(adj, packed);
    gat_prep<<<N / 16, 256, 0, stream>>>(h, W, a, WhT, fsrc, fdst);
    gat_main<<<(N / 64) * jsplit, 256, 0, stream>>>(packed, fsrc, fdst, WhT, nump, denp, jsplit, jlen);
    gat_final<<<(N * FOUT) / 256, 256, 0, stream>>>(nump, denp, out, jsplit);
}

// Round 4
// 149.110 us; speedup vs baseline: 1.1490x; 1.0938x over previous
//
#include <hip/hip_runtime.h>

typedef __attribute__((ext_vector_type(8))) short bf16x8;
typedef __attribute__((ext_vector_type(4))) float f32x4;

#define N 8192
#define FIN 512
#define FOUT 64
#define NP (N + 32)     // padded WhT row stride (shorts)
#define JSPLIT 16
#define JLEN 512        // N / JSPLIT
#define LROW 528        // LDS adj-byte row stride (512 + 16) — breaks bank alias

// round-to-nearest-even f32 -> bf16 (inputs are never NaN here)
static __device__ __forceinline__ short f2bf(float x) {
    unsigned u = __float_as_uint(x);
    u += 0x7FFFu + ((u >> 16) & 1u);
    return (short)(u >> 16);
}

// p = byte ? exp(leakyrelu(s, 0.2)) : 0
static __device__ __forceinline__ float pb(unsigned dw, int k, float s) {
    float p = __expf(fmaxf(s, 0.2f * s));
    return ((dw >> (8 * k)) & 1u) ? p : 0.f;
}

// Pass A: Wh = h@W (f32 accum); store Wh^T as bf16 [FOUT][NP]; f_src/f_dst f32 [N].
__global__ __launch_bounds__(256) void gat_prep(const float* __restrict__ h,
    const float* __restrict__ W, const float* __restrict__ a,
    short* __restrict__ WhT, float* __restrict__ fsrc, float* __restrict__ fdst)
{
    __shared__ float lds[FOUT][16];
    const int i0 = blockIdx.x * 16;
    const int w = threadIdx.x >> 6, f = threadIdx.x & 63;
    const int ir = i0 + w * 4;
    const float* h0 = h + (size_t)ir * FIN;
    float acc0 = 0.f, acc1 = 0.f, acc2 = 0.f, acc3 = 0.f;
    for (int k = 0; k < FIN; k += 4) {
        float wv0 = W[(k + 0) * FOUT + f];
        float wv1 = W[(k + 1) * FOUT + f];
        float wv2 = W[(k + 2) * FOUT + f];
        float wv3 = W[(k + 3) * FOUT + f];
        float4 h0v = *(const float4*)(h0 + k);
        float4 h1v = *(const float4*)(h0 + FIN + k);
        float4 h2v = *(const float4*)(h0 + 2 * FIN + k);
        float4 h3v = *(const float4*)(h0 + 3 * FIN + k);
        acc0 = fmaf(h0v.w, wv3, fmaf(h0v.z, wv2, fmaf(h0v.y, wv1, fmaf(h0v.x, wv0, acc0))));
        acc1 = fmaf(h1v.w, wv3, fmaf(h1v.z, wv2, fmaf(h1v.y, wv1, fmaf(h1v.x, wv0, acc1))));
        acc2 = fmaf(h2v.w, wv3, fmaf(h2v.z, wv2, fmaf(h2v.y, wv1, fmaf(h2v.x, wv0, acc2))));
        acc3 = fmaf(h3v.w, wv3, fmaf(h3v.z, wv2, fmaf(h3v.y, wv1, fmaf(h3v.x, wv0, acc3))));
    }
    const float as = a[f], ad = a[FOUT + f];
    float s0 = acc0 * as, s1 = acc1 * as, s2 = acc2 * as, s3 = acc3 * as;
    float d0 = acc0 * ad, d1 = acc1 * ad, d2 = acc2 * ad, d3 = acc3 * ad;
    #pragma unroll
    for (int m = 1; m < 64; m <<= 1) {
        s0 += __shfl_xor(s0, m); s1 += __shfl_xor(s1, m);
        s2 += __shfl_xor(s2, m); s3 += __shfl_xor(s3, m);
        d0 += __shfl_xor(d0, m); d1 += __shfl_xor(d1, m);
        d2 += __shfl_xor(d2, m); d3 += __shfl_xor(d3, m);
    }
    if (f == 0) {
        fsrc[ir + 0] = s0; fsrc[ir + 1] = s1; fsrc[ir + 2] = s2; fsrc[ir + 3] = s3;
        fdst[ir + 0] = d0; fdst[ir + 1] = d1; fdst[ir + 2] = d2; fdst[ir + 3] = d3;
    }
    lds[f][w * 4 + 0] = acc0;
    lds[f][w * 4 + 1] = acc1;
    lds[f][w * 4 + 2] = acc2;
    lds[f][w * 4 + 3] = acc3;
    __syncthreads();
    const int ff = threadIdx.x >> 2, q = threadIdx.x & 3;
    short4 o;
    o.x = f2bf(lds[ff][q * 4 + 0]);
    o.y = f2bf(lds[ff][q * 4 + 1]);
    o.z = f2bf(lds[ff][q * 4 + 2]);
    o.w = f2bf(lds[ff][q * 4 + 3]);
    *(short4*)(WhT + (size_t)ff * NP + i0 + q * 4) = o;
}

// Fused pass: block = 64 rows x JLEN cols, 4 waves; wave w owns rows [i0+16w, +16).
// Phase 1 (per wave, no barrier needed — LDS region is wave-private): stream the
// wave's 16 adj row-segments contiguously (int4/lane = 1KiB/instr), pack 0/1 ints
// to bytes, store to LDS.
// Phase 2: lane l: A-row = l&15, j-group g = l>>4 (8 consecutive j). adj bytes from
// LDS; Wh^T fragments from L2; P@Wh via mfma_f32_16x16x32_bf16; den in f32.
__global__ __launch_bounds__(256) void gat_fused(const int* __restrict__ adj,
    const float* __restrict__ fsrc, const float* __restrict__ fdst,
    const short* __restrict__ WhT, float* __restrict__ nump, float* __restrict__ denp)
{
    __shared__ unsigned char ab[64 * LROW];
    const int ib = blockIdx.x >> 4;            // / JSPLIT
    const int js = blockIdx.x & (JSPLIT - 1);
    const int i0 = ib * 64, jb = js * JLEN;
    const int l = threadIdx.x & 63, w = threadIdx.x >> 6;

    // ---- Phase 1: pack this wave's 16 adjacency row-segments into LDS bytes ----
    #pragma unroll 4
    for (int r = 0; r < 16; ++r) {
        const int il = w * 16 + r;
        const int* src = adj + (size_t)(i0 + il) * N + jb;
        #pragma unroll
        for (int c = 0; c < 2; ++c) {
            int4 v = *(const int4*)(src + c * 256 + l * 4);
            unsigned b = (unsigned)(v.x & 1) | ((unsigned)(v.y & 1) << 8) |
                         ((unsigned)(v.z & 1) << 16) | ((unsigned)(v.w & 1) << 24);
            *(unsigned*)&ab[il * LROW + c * 256 + l * 4] = b;
        }
    }

    // ---- Phase 2: MFMA over the tile ----
    const int rl = l & 15, g = l >> 4;
    const int il = w * 16 + rl;
    const int i = i0 + il;
    const float fs = fsrc[i];
    const short* bbase = WhT + (size_t)rl * NP + jb + g * 8;
    const float* ebase = fdst + jb + g * 8;
    f32x4 acc0{0.f, 0.f, 0.f, 0.f}, acc1{0.f, 0.f, 0.f, 0.f};
    f32x4 acc2{0.f, 0.f, 0.f, 0.f}, acc3{0.f, 0.f, 0.f, 0.f};
    float den = 0.f;
    #pragma unroll 2
    for (int s = 0; s < JLEN / 32; ++s) {
        uint2 bv = *(const uint2*)&ab[il * LROW + s * 32 + g * 8];
        float4 e0 = *(const float4*)(ebase + s * 32);
        float4 e1 = *(const float4*)(ebase + s * 32 + 4);
        bf16x8 b0 = *(const bf16x8*)(bbase + s * 32);
        bf16x8 b1 = *(const bf16x8*)(bbase + 16 * NP + s * 32);
        bf16x8 b2 = *(const bf16x8*)(bbase + 32 * NP + s * 32);
        bf16x8 b3 = *(const bf16x8*)(bbase + 48 * NP + s * 32);
        float p0 = pb(bv.x, 0, fs + e0.x);
        float p1 = pb(bv.x, 1, fs + e0.y);
        float p2 = pb(bv.x, 2, fs + e0.z);
        float p3 = pb(bv.x, 3, fs + e0.w);
        float p4 = pb(bv.y, 0, fs + e1.x);
        float p5 = pb(bv.y, 1, fs + e1.y);
        float p6 = pb(bv.y, 2, fs + e1.z);
        float p7 = pb(bv.y, 3, fs + e1.w);
        den += ((p0 + p1) + (p2 + p3)) + ((p4 + p5) + (p6 + p7));
        bf16x8 af;
        af[0] = f2bf(p0); af[1] = f2bf(p1); af[2] = f2bf(p2); af[3] = f2bf(p3);
        af[4] = f2bf(p4); af[5] = f2bf(p5); af[6] = f2bf(p6); af[7] = f2bf(p7);
        acc0 = __builtin_amdgcn_mfma_f32_16x16x32_bf16(af, b0, acc0, 0, 0, 0);
        acc1 = __builtin_amdgcn_mfma_f32_16x16x32_bf16(af, b1, acc1, 0, 0, 0);
        acc2 = __builtin_amdgcn_mfma_f32_16x16x32_bf16(af, b2, acc2, 0, 0, 0);
        acc3 = __builtin_amdgcn_mfma_f32_16x16x32_bf16(af, b3, acc3, 0, 0, 0);
    }

    den += __shfl_xor(den, 16);
    den += __shfl_xor(den, 32);
    if (l < 16) denp[(size_t)js * N + i0 + w * 16 + l] = den;
    // C/D layout: col = l&15, row = (l>>4)*4 + reg
    float* np = nump + (size_t)js * N * FOUT + (size_t)(i0 + w * 16) * FOUT;
    #pragma unroll
    for (int q = 0; q < 4; ++q) {
        const int orow = g * 4 + q;
        np[(size_t)orow * FOUT + 0  + rl] = acc0[q];
        np[(size_t)orow * FOUT + 16 + rl] = acc1[q];
        np[(size_t)orow * FOUT + 32 + rl] = acc2[q];
        np[(size_t)orow * FOUT + 48 + rl] = acc3[q];
    }
}

// Pass C: out = elu(num/den)
__global__ __launch_bounds__(256) void gat_final(const float* __restrict__ nump,
    const float* __restrict__ denp, float* __restrict__ out)
{
    const int t = blockIdx.x * 256 + threadIdx.x;
    const int i = t >> 6;
    float num = 0.f, den = 0.f;
    for (int js = 0; js < JSPLIT; ++js) {
        num += nump[(size_t)js * N * FOUT + t];
        den += denp[(size_t)js * N + i];
    }
    const float x = num / den;
    out[t] = x > 0.f ? x : expm1f(x);
}

extern "C" void kernel_launch(void* const* d_in, const int* in_sizes, int n_in,
                              void* d_out, int out_size, void* d_ws, size_t ws_size,
                              hipStream_t stream) {
    const float* h   = (const float*)d_in[0];
    const int*   adj = (const int*)d_in[1];
    const float* W   = (const float*)d_in[2];
    const float* a   = (const float*)d_in[3];
    float* out = (float*)d_out;

    char* ws = (char*)d_ws;
    short* WhT  = (short*)ws;                          // 64*NP*2 ~ 1.03 MiB
    float* fsrc = (float*)(ws + (size_t)FOUT * NP * 2); // 32 KiB
    float* fdst = fsrc + N;                            // 32 KiB
    float* nump = fdst + N;                            // JSPLIT * 2 MiB
    float* denp = nump + (size_t)JSPLIT * N * FOUT;    // JSPLIT * 32 KiB

    gat_prep<<<N / 16, 256, 0, stream>>>(h, W, a, WhT, fsrc, fdst);
    gat_fused<<<(N / 64) * JSPLIT, 256, 0, stream>>>(adj, fsrc, fdst, WhT, nump, denp);
    gat_final<<<(N * FOUT) / 256, 256, 0, stream>>>(nump, denp, out);
}

// Round 5
// 128.638 us; speedup vs baseline: 1.3319x; 1.1592x over previous
//
#include <hip/hip_runtime.h>

typedef __attribute__((ext_vector_type(8))) short bf16x8;
typedef __attribute__((ext_vector_type(4))) float f32x4;

#define N 8192
#define FIN 512
#define FOUT 64
#define NP (N + 32)        // padded WhT row stride (shorts)
#define JSPLIT 8
#define JSPAN 1024         // j per block
#define NCHUNK 16          // chunks per block (64 j each)

// LDS per buffer: adj [64 rows][256 B] + B frags [8][1024 B] + fd [256 B]
#define ADJ_SZ 16384
#define B_SZ   8192
#define FD_SZ  256
#define BUF_SZ (ADJ_SZ + B_SZ + FD_SZ)   // 24832 B; x2 = 49664 B -> 3 blocks/CU

// round-to-nearest-even f32 -> bf16
static __device__ __forceinline__ short f2bf(float x) {
    unsigned u = __float_as_uint(x);
    u += 0x7FFFu + ((u >> 16) & 1u);
    return (short)(u >> 16);
}

// p = av>0 ? exp(leakyrelu(s, 0.2)) : 0
static __device__ __forceinline__ float pedge(int av, float s) {
    float p = __expf(fmaxf(s, 0.2f * s));
    return av > 0 ? p : 0.f;
}

// async global->LDS: dest = wave-uniform base + lane*size; src is PER-LANE
static __device__ __forceinline__ void gload16(const void* g, void* l) {
    __builtin_amdgcn_global_load_lds(
        (const __attribute__((address_space(1))) void*)g,
        (__attribute__((address_space(3))) void*)l, 16, 0, 0);
}
static __device__ __forceinline__ void gload4(const void* g, void* l) {
    __builtin_amdgcn_global_load_lds(
        (const __attribute__((address_space(1))) void*)g,
        (__attribute__((address_space(3))) void*)l, 4, 0, 0);
}

#define SCHED0() __builtin_amdgcn_sched_barrier(0)
#define SBAR()   __builtin_amdgcn_s_barrier()

// Pass A: Wh = h@W (f32 accum); store Wh^T as bf16 [FOUT][NP]; f_src/f_dst f32 [N].
__global__ __launch_bounds__(256) void gat_prep(const float* __restrict__ h,
    const float* __restrict__ W, const float* __restrict__ a,
    short* __restrict__ WhT, float* __restrict__ fsrc, float* __restrict__ fdst)
{
    __shared__ float lds[FOUT][16];
    const int i0 = blockIdx.x * 16;
    const int w = threadIdx.x >> 6, f = threadIdx.x & 63;
    const int ir = i0 + w * 4;
    const float* h0 = h + (size_t)ir * FIN;
    float acc0 = 0.f, acc1 = 0.f, acc2 = 0.f, acc3 = 0.f;
    for (int k = 0; k < FIN; k += 4) {
        float wv0 = W[(k + 0) * FOUT + f];
        float wv1 = W[(k + 1) * FOUT + f];
        float wv2 = W[(k + 2) * FOUT + f];
        float wv3 = W[(k + 3) * FOUT + f];
        float4 h0v = *(const float4*)(h0 + k);
        float4 h1v = *(const float4*)(h0 + FIN + k);
        float4 h2v = *(const float4*)(h0 + 2 * FIN + k);
        float4 h3v = *(const float4*)(h0 + 3 * FIN + k);
        acc0 = fmaf(h0v.w, wv3, fmaf(h0v.z, wv2, fmaf(h0v.y, wv1, fmaf(h0v.x, wv0, acc0))));
        acc1 = fmaf(h1v.w, wv3, fmaf(h1v.z, wv2, fmaf(h1v.y, wv1, fmaf(h1v.x, wv0, acc1))));
        acc2 = fmaf(h2v.w, wv3, fmaf(h2v.z, wv2, fmaf(h2v.y, wv1, fmaf(h2v.x, wv0, acc2))));
        acc3 = fmaf(h3v.w, wv3, fmaf(h3v.z, wv2, fmaf(h3v.y, wv1, fmaf(h3v.x, wv0, acc3))));
    }
    const float as = a[f], ad = a[FOUT + f];
    float s0 = acc0 * as, s1 = acc1 * as, s2 = acc2 * as, s3 = acc3 * as;
    float d0 = acc0 * ad, d1 = acc1 * ad, d2 = acc2 * ad, d3 = acc3 * ad;
    #pragma unroll
    for (int m = 1; m < 64; m <<= 1) {
        s0 += __shfl_xor(s0, m); s1 += __shfl_xor(s1, m);
        s2 += __shfl_xor(s2, m); s3 += __shfl_xor(s3, m);
        d0 += __shfl_xor(d0, m); d1 += __shfl_xor(d1, m);
        d2 += __shfl_xor(d2, m); d3 += __shfl_xor(d3, m);
    }
    if (f == 0) {
        fsrc[ir + 0] = s0; fsrc[ir + 1] = s1; fsrc[ir + 2] = s2; fsrc[ir + 3] = s3;
        fdst[ir + 0] = d0; fdst[ir + 1] = d1; fdst[ir + 2] = d2; fdst[ir + 3] = d3;
    }
    lds[f][w * 4 + 0] = acc0;
    lds[f][w * 4 + 1] = acc1;
    lds[f][w * 4 + 2] = acc2;
    lds[f][w * 4 + 3] = acc3;
    __syncthreads();
    const int ff = threadIdx.x >> 2, q = threadIdx.x & 3;
    short4 o;
    o.x = f2bf(lds[ff][q * 4 + 0]);
    o.y = f2bf(lds[ff][q * 4 + 1]);
    o.z = f2bf(lds[ff][q * 4 + 2]);
    o.w = f2bf(lds[ff][q * 4 + 3]);
    *(short4*)(WhT + (size_t)ff * NP + i0 + q * 4) = o;
}

// Stage one 64-j chunk into buf via global_load_lds: exactly 7 vmem instrs/wave.
static __device__ __forceinline__ void stage_chunk(
    const int* __restrict__ adj, const short* __restrict__ WhT,
    const float* __restrict__ fdst, int i0, int jc, int w, int l, char* buf)
{
    const int rsub = l >> 4, csub = l & 15;
    // adj: 4 instrs; instr n covers rows w*16+4n..+3; 1 KiB linear per instr
    #pragma unroll
    for (int n = 0; n < 4; ++n) {
        const int r = w * 16 + n * 4 + rsub;
        const char* src = (const char*)(adj + (size_t)(i0 + r) * N + jc) + csub * 16;
        gload16(src, buf + (w * 16 + n * 4) * 256);
    }
    // B: 2 instrs; m=w*2+mm -> (s=m>>2, q=m&3); lane holds WhT[q*16+csub][j..j+7]
    #pragma unroll
    for (int mm = 0; mm < 2; ++mm) {
        const int m = w * 2 + mm;
        const int s = m >> 2, q = m & 3;
        const char* src = (const char*)(WhT + (size_t)(q * 16 + csub) * NP + jc + s * 32 + rsub * 8);
        gload16(src, buf + ADJ_SZ + m * 1024);
    }
    // fd: 1 instr (all 4 waves write identical data to same slots - benign)
    gload4((const char*)(fdst + jc + l), buf + ADJ_SZ + B_SZ);
}

// Fused pass: block = 64 rows x 1024 j (8 j-splits); 16 double-buffered 64-j chunks.
// 2-phase pipeline: stage(t+1) async -> counted vmcnt(7) -> barrier -> compute(t).
__global__ __launch_bounds__(256) void gat_fused(const int* __restrict__ adj,
    const float* __restrict__ fsrc, const float* __restrict__ fdst,
    const short* __restrict__ WhT, float* __restrict__ nump, float* __restrict__ denp)
{
    __shared__ int4 smem4[2 * BUF_SZ / 16];
    char* smem = (char*)smem4;
    const int ib = blockIdx.x >> 3;            // / JSPLIT
    const int js = blockIdx.x & (JSPLIT - 1);
    const int i0 = ib * 64, jb = js * JSPAN;
    const int l = threadIdx.x & 63, w = threadIdx.x >> 6;
    const int rl = l & 15, g = l >> 4;
    const int rloc = w * 16 + rl;
    const float fs = fsrc[i0 + rloc];

    f32x4 acc0{0.f, 0.f, 0.f, 0.f}, acc1{0.f, 0.f, 0.f, 0.f};
    f32x4 acc2{0.f, 0.f, 0.f, 0.f}, acc3{0.f, 0.f, 0.f, 0.f};
    float den = 0.f;

    stage_chunk(adj, WhT, fdst, i0, jb, w, l, smem);            // prologue: chunk 0

    for (int t = 0; t < NCHUNK; ++t) {
        char* cbuf = smem + (t & 1) * BUF_SZ;
        char* nbuf = smem + ((t + 1) & 1) * BUF_SZ;
        if (t + 1 < NCHUNK) {
            stage_chunk(adj, WhT, fdst, i0, jb + (t + 1) * 64, w, l, nbuf);
            SCHED0();
            asm volatile("s_waitcnt vmcnt(7)" ::: "memory");    // prev chunk landed
            SCHED0();
        } else {
            SCHED0();
            asm volatile("s_waitcnt vmcnt(0)" ::: "memory");
            SCHED0();
        }
        SBAR();                                                  // all waves' stage done
        SCHED0();

        const char* adjb = cbuf;
        const char* bb   = cbuf + ADJ_SZ;
        const char* fdb  = cbuf + ADJ_SZ + B_SZ;
        #pragma unroll
        for (int s = 0; s < 2; ++s) {
            int4 a0 = *(const int4*)(adjb + rloc * 256 + s * 128 + g * 32);
            int4 a1 = *(const int4*)(adjb + rloc * 256 + s * 128 + g * 32 + 16);
            float4 e0 = *(const float4*)(fdb + (s * 32 + g * 8) * 4);
            float4 e1 = *(const float4*)(fdb + (s * 32 + g * 8) * 4 + 16);
            bf16x8 b0 = *(const bf16x8*)(bb + ((s * 4 + 0) * 64 + l) * 16);
            bf16x8 b1 = *(const bf16x8*)(bb + ((s * 4 + 1) * 64 + l) * 16);
            bf16x8 b2 = *(const bf16x8*)(bb + ((s * 4 + 2) * 64 + l) * 16);
            bf16x8 b3 = *(const bf16x8*)(bb + ((s * 4 + 3) * 64 + l) * 16);
            float p0 = pedge(a0.x, fs + e0.x);
            float p1 = pedge(a0.y, fs + e0.y);
            float p2 = pedge(a0.z, fs + e0.z);
            float p3 = pedge(a0.w, fs + e0.w);
            float p4 = pedge(a1.x, fs + e1.x);
            float p5 = pedge(a1.y, fs + e1.y);
            float p6 = pedge(a1.z, fs + e1.z);
            float p7 = pedge(a1.w, fs + e1.w);
            den += ((p0 + p1) + (p2 + p3)) + ((p4 + p5) + (p6 + p7));
            bf16x8 af;
            af[0] = f2bf(p0); af[1] = f2bf(p1); af[2] = f2bf(p2); af[3] = f2bf(p3);
            af[4] = f2bf(p4); af[5] = f2bf(p5); af[6] = f2bf(p6); af[7] = f2bf(p7);
            acc0 = __builtin_amdgcn_mfma_f32_16x16x32_bf16(af, b0, acc0, 0, 0, 0);
            acc1 = __builtin_amdgcn_mfma_f32_16x16x32_bf16(af, b1, acc1, 0, 0, 0);
            acc2 = __builtin_amdgcn_mfma_f32_16x16x32_bf16(af, b2, acc2, 0, 0, 0);
            acc3 = __builtin_amdgcn_mfma_f32_16x16x32_bf16(af, b3, acc3, 0, 0, 0);
        }
        SCHED0();
        SBAR();                // protect cbuf before next iter restages into it
        SCHED0();
    }

    den += __shfl_xor(den, 16);
    den += __shfl_xor(den, 32);
    if (l < 16) denp[(size_t)js * N + i0 + w * 16 + l] = den;
    // C/D layout: col = l&15, row = (l>>4)*4 + reg
    float* np = nump + (size_t)js * N * FOUT + (size_t)(i0 + w * 16) * FOUT;
    #pragma unroll
    for (int q = 0; q < 4; ++q) {
        const int orow = g * 4 + q;
        np[(size_t)orow * FOUT + 0  + rl] = acc0[q];
        np[(size_t)orow * FOUT + 16 + rl] = acc1[q];
        np[(size_t)orow * FOUT + 32 + rl] = acc2[q];
        np[(size_t)orow * FOUT + 48 + rl] = acc3[q];
    }
}

// Pass C: out = elu(num/den)
__global__ __launch_bounds__(256) void gat_final(const float* __restrict__ nump,
    const float* __restrict__ denp, float* __restrict__ out)
{
    const int t = blockIdx.x * 256 + threadIdx.x;
    const int i = t >> 6;
    float num = 0.f, den = 0.f;
    for (int js = 0; js < JSPLIT; ++js) {
        num += nump[(size_t)js * N * FOUT + t];
        den += denp[(size_t)js * N + i];
    }
    const float x = num / den;
    out[t] = x > 0.f ? x : expm1f(x);
}

extern "C" void kernel_launch(void* const* d_in, const int* in_sizes, int n_in,
                              void* d_out, int out_size, void* d_ws, size_t ws_size,
                              hipStream_t stream) {
    const float* h   = (const float*)d_in[0];
    const int*   adj = (const int*)d_in[1];
    const float* W   = (const float*)d_in[2];
    const float* a   = (const float*)d_in[3];
    float* out = (float*)d_out;

    char* ws = (char*)d_ws;
    short* WhT  = (short*)ws;                           // 64*NP*2 ~ 1.03 MiB
    float* fsrc = (float*)(ws + (size_t)FOUT * NP * 2); // 32 KiB
    float* fdst = fsrc + N;                             // 32 KiB
    float* nump = fdst + N;                             // JSPLIT * 2 MiB
    float* denp = nump + (size_t)JSPLIT * N * FOUT;     // JSPLIT * 32 KiB

    gat_prep<<<N / 16, 256, 0, stream>>>(h, W, a, WhT, fsrc, fdst);
    gat_fused<<<(N / 64) * JSPLIT, 256, 0, stream>>>(adj, fsrc, fdst, WhT, nump, denp);
    gat_final<<<(N * FOUT) / 256, 256, 0, stream>>>(nump, denp, out);
}